// Round 1
// 1841.648 us; speedup vs baseline: 1.2092x; 1.2092x over previous
//
#include <hip/hip_runtime.h>
#include <hip/hip_bf16.h>

#define S 8192
#define H 1024
#define DFF 2048
#define E 64
#define CAP 512

typedef __attribute__((ext_vector_type(8))) short short8;
typedef __attribute__((ext_vector_type(4))) float floatx4;
typedef unsigned short u16;

__device__ inline unsigned pack_bf16x2(float a, float b) {
    __hip_bfloat162 h2 = __float22bfloat162_rn(make_float2(a, b));
    return *(unsigned*)&h2;
}

// async global->LDS, 16B/lane; LDS dest is wave-uniform base + lane*16
__device__ inline void async_load16(const void* g, u16* l) {
    __builtin_amdgcn_global_load_lds(
        (const __attribute__((address_space(1))) unsigned*)g,
        (__attribute__((address_space(3))) unsigned*)l, 16, 0, 0);
}

// ---------------- init: counters + slot->token map ----------------
__global__ void k_init(int* __restrict__ cnt, int* __restrict__ tok_slot) {
    int i = blockIdx.x * 256 + threadIdx.x;
    if (i < E * CAP) tok_slot[i] = -1;
    if (i < E) cnt[i] = 0;
}

// ---------------- rmsnorm + router + dispatch (8 tokens/block) ----------------
__global__ __launch_bounds__(256) void k_rms_router(
    const float* __restrict__ x, const float* __restrict__ rms_w,
    const float* __restrict__ router_w, float* __restrict__ out,
    u16* __restrict__ xn, int* __restrict__ cnt,
    int* __restrict__ tok_slot, float* __restrict__ w_slot)
{
    __shared__ float xs[8 * 1024];
    __shared__ float sco[8 * 64];
    __shared__ float invs[8];
    const int tid = threadIdx.x;
    const int t0 = blockIdx.x * 8;

    const float4* xg = (const float4*)(x + (size_t)t0 * H);
    float4* og = (float4*)(out + (size_t)t0 * H);
    float4* xs4 = (float4*)xs;
    for (int i = tid; i < 2048; i += 256) { float4 v = xg[i]; xs4[i] = v; og[i] = v; }
    __syncthreads();

    const int wv = tid >> 6, ln = tid & 63;
    for (int rr = 0; rr < 2; rr++) {
        int row = wv * 2 + rr;
        const float* p = xs + row * 1024;
        float s = 0.f;
        #pragma unroll
        for (int j = 0; j < 16; j++) { float v = p[ln + 64 * j]; s += v * v; }
        #pragma unroll
        for (int m = 32; m; m >>= 1) s += __shfl_xor(s, m);
        if (ln == 0) invs[row] = rsqrtf(s * (1.0f / 1024.0f) + 1e-6f);
    }
    __syncthreads();

    unsigned* xng = (unsigned*)(xn + (size_t)t0 * H);
    for (int i = tid; i < 4096; i += 256) {
        int e0 = 2 * i;
        int row = e0 >> 10;
        int c0 = e0 & 1023;
        float iv = invs[row];
        float v0 = xs[e0] * iv * rms_w[c0];
        float v1 = xs[e0 + 1] * iv * rms_w[c0 + 1];
        xs[e0] = v0; xs[e0 + 1] = v1;
        xng[i] = pack_bf16x2(v0, v1);
    }
    __syncthreads();

    for (int ee = 0; ee < 16; ee++) {
        int e = wv * 16 + ee;
        const float* rw = router_w + e * 1024;
        float rv[16];
        #pragma unroll
        for (int j = 0; j < 16; j++) rv[j] = rw[ln + 64 * j];
        for (int t = 0; t < 8; t++) {
            float p = 0.f;
            #pragma unroll
            for (int j = 0; j < 16; j++) p += rv[j] * xs[t * 1024 + ln + 64 * j];
            #pragma unroll
            for (int m = 32; m; m >>= 1) p += __shfl_xor(p, m);
            if (ln == 0) sco[t * 64 + e] = p;
        }
    }
    __syncthreads();

    if (tid < 8) {
        int t = tid;
        float v0 = -1e30f, v1 = -1e30f; int i0 = 0, i1 = 0;
        for (int e = 0; e < 64; e++) {
            float s = sco[t * 64 + e];
            if (s > v0) { v1 = v0; i1 = i0; v0 = s; i0 = e; }
            else if (s > v1) { v1 = s; i1 = e; }
        }
        float e1 = __expf(v1 - v0);
        float w0 = 1.0f / (1.0f + e1);
        float w1v = e1 * w0;
        int tok = t0 + t;
        int p0 = atomicAdd(&cnt[i0], 1);
        if (p0 < CAP) { tok_slot[i0 * CAP + p0] = tok; w_slot[i0 * CAP + p0] = w0; }
        int p1 = atomicAdd(&cnt[i1], 1);
        if (p1 < CAP) { tok_slot[i1 * CAP + p1] = tok; w_slot[i1 * CAP + p1] = w1v; }
    }
}

// ---------------- GEMM1: h[e] = silu(gather(xn) @ w1[e]^T), bf16 out ----------------
// 128x128 tile, BK=64, double-buffered LDS, 1 barrier/K-step.
// A (bf16) via global_load_lds with pre-swizzled source; B (fp32) reg-staged+packed.
__global__ __launch_bounds__(256) void k_gemm1(
    const u16* __restrict__ xn, const float* __restrict__ w1,
    u16* __restrict__ h, const int* __restrict__ cnt,
    const int* __restrict__ tok_slot)
{
    // XCD-chunked bijective remap (4096 % 8 == 0): each XCD gets 8 whole experts,
    // so the 2-3 active mt tiles sharing a w1 (e,nt)-panel hit the same L2.
    const int flat = blockIdx.y * 64 + blockIdx.x;
    const int logical = (flat & 7) * 512 + (flat >> 3);
    const int e  = logical >> 6;
    const int nt = (logical & 63) >> 2;   // 0..15
    const int mt = logical & 3;           // 0..3

    int c = cnt[e]; if (c > CAP) c = CAP;
    if (mt * 128 >= c) return;

    __shared__ __align__(16) u16 lA[2][128 * 64];
    __shared__ __align__(16) u16 lB[2][128 * 64];
    __shared__ int toks[128];
    const int tid = threadIdx.x;
    if (tid < 128) {
        int tk = tok_slot[e * CAP + mt * 128 + tid];
        toks[tid] = tk < 0 ? 0 : tk;
    }
    __syncthreads();

    const int wv = tid >> 6, ln = tid & 63;
    u16* const lA0 = &lA[0][0];
    u16* const lB0 = &lB[0][0];

    // A: chunk = i*256+tid lands at LDS byte chunk*16 (linear). Physical slot
    // s=chunk&7 of row=chunk>>3 must hold logical col16 (s ^ (row&7)).
    const u16* asrc[4];
    int aofs[4];
    #pragma unroll
    for (int i = 0; i < 4; i++) {
        int chunk = i * 256 + tid;
        int row = chunk >> 3, s = chunk & 7;
        asrc[i] = xn + (size_t)toks[row] * H + ((s ^ (row & 7)) << 3);
        aofs[i] = (i * 256 + wv * 64) << 3;   // wave-uniform elem offset
    }

    // B: row = tid>>1, half-row seg = tid&1 (32 fp32 each); swizzled ds_write.
    const int brow = tid >> 1, bseg = tid & 1;
    const float* bsrc = w1 + ((size_t)e * DFF + nt * 128 + brow) * H + bseg * 32;
    int bofs[4];
    #pragma unroll
    for (int j = 0; j < 4; j++)
        bofs[j] = brow * 64 + (((bseg * 4 + j) ^ (brow & 7)) << 3);

    float4 bv[8];
    auto loadB = [&](int k0) {
        const float4* b4 = (const float4*)(bsrc + k0);
        #pragma unroll
        for (int j = 0; j < 8; j++) bv[j] = b4[j];
    };
    auto stageA = [&](int k0, int buf) {
        #pragma unroll
        for (int i = 0; i < 4; i++)
            async_load16(asrc[i] + k0, lA0 + buf * 8192 + aofs[i]);
    };
    auto writeB = [&](int buf) {
        #pragma unroll
        for (int j = 0; j < 4; j++) {
            uint4 p;
            p.x = pack_bf16x2(bv[2 * j].x, bv[2 * j].y);
            p.y = pack_bf16x2(bv[2 * j].z, bv[2 * j].w);
            p.z = pack_bf16x2(bv[2 * j + 1].x, bv[2 * j + 1].y);
            p.w = pack_bf16x2(bv[2 * j + 1].z, bv[2 * j + 1].w);
            *(uint4*)(lB0 + buf * 8192 + bofs[j]) = p;
        }
    };

    const int wr = wv >> 1, wc = wv & 1;
    const int quad = ln >> 4, lq = ln & 15;
    floatx4 acc[4][4] = {};
    auto compute = [&](int buf) {
        #pragma unroll
        for (int kk = 0; kk < 64; kk += 32) {
            short8 af[4], bf[4];
            #pragma unroll
            for (int mi = 0; mi < 4; mi++)
                af[mi] = *(const short8*)(lA0 + buf * 8192 + (wr * 64 + mi * 16 + lq) * 64
                                          + ((((kk >> 3) + quad) ^ (lq & 7)) << 3));
            #pragma unroll
            for (int ni = 0; ni < 4; ni++)
                bf[ni] = *(const short8*)(lB0 + buf * 8192 + (wc * 64 + ni * 16 + lq) * 64
                                          + ((((kk >> 3) + quad) ^ (lq & 7)) << 3));
            #pragma unroll
            for (int mi = 0; mi < 4; mi++)
                #pragma unroll
                for (int ni = 0; ni < 4; ni++)
                    acc[mi][ni] = __builtin_amdgcn_mfma_f32_16x16x32_bf16(af[mi], bf[ni], acc[mi][ni], 0, 0, 0);
        }
    };

    // pipeline: prefetch t+1 while computing t; one barrier per step
    loadB(0);
    stageA(0, 0);
    writeB(0);
    __syncthreads();
    for (int t = 0; t < 15; ++t) {
        const int cur = t & 1, nxt = cur ^ 1;
        const int k0 = (t + 1) * 64;
        loadB(k0);         // fp32 B(t+1) -> regs, in flight over MFMA
        stageA(k0, nxt);   // bf16 A(t+1) -> LDS, drained by pre-barrier vmcnt
        compute(cur);
        writeB(nxt);       // waits only on bv
        __syncthreads();
    }
    compute(1);            // t = 15

    // epilogue: silu -> bf16
    #pragma unroll
    for (int mi = 0; mi < 4; mi++) {
        #pragma unroll
        for (int r = 0; r < 4; r++) {
            int row = mt * 128 + wr * 64 + mi * 16 + quad * 4 + r;
            u16* hp = h + ((size_t)e * CAP + row) * DFF + nt * 128 + wc * 64 + lq;
            #pragma unroll
            for (int ni = 0; ni < 4; ni++) {
                float v = acc[mi][ni][r];
                float sv = v / (1.0f + __expf(-v));
                __hip_bfloat16 bb = __float2bfloat16(sv);
                hp[ni * 16] = *(u16*)&bb;
            }
        }
    }
}

// ---------------- GEMM2: out[tok] += w * (h[e] @ w2[e]^T) ----------------
__global__ __launch_bounds__(256) void k_gemm2(
    const u16* __restrict__ hb, const float* __restrict__ w2,
    float* __restrict__ out, const int* __restrict__ cnt,
    const int* __restrict__ tok_slot, const float* __restrict__ w_slot)
{
    const int flat = blockIdx.y * 32 + blockIdx.x;   // 2048 % 8 == 0
    const int logical = (flat & 7) * 256 + (flat >> 3);
    const int e  = logical >> 5;
    const int nt = (logical & 31) >> 2;   // 0..7
    const int mt = logical & 3;

    int c = cnt[e]; if (c > CAP) c = CAP;
    if (mt * 128 >= c) return;

    __shared__ __align__(16) u16 lA[2][128 * 64];
    __shared__ __align__(16) u16 lB[2][128 * 64];
    const int tid = threadIdx.x;
    const int wv = tid >> 6, ln = tid & 63;
    u16* const lA0 = &lA[0][0];
    u16* const lB0 = &lB[0][0];

    const u16* asrc[4];
    int aofs[4];
    #pragma unroll
    for (int i = 0; i < 4; i++) {
        int chunk = i * 256 + tid;
        int row = chunk >> 3, s = chunk & 7;
        asrc[i] = hb + ((size_t)e * CAP + mt * 128 + row) * DFF + ((s ^ (row & 7)) << 3);
        aofs[i] = (i * 256 + wv * 64) << 3;
    }

    const int brow = tid >> 1, bseg = tid & 1;
    const float* bsrc = w2 + ((size_t)e * H + nt * 128 + brow) * DFF + bseg * 32;
    int bofs[4];
    #pragma unroll
    for (int j = 0; j < 4; j++)
        bofs[j] = brow * 64 + (((bseg * 4 + j) ^ (brow & 7)) << 3);

    float4 bv[8];
    auto loadB = [&](int k0) {
        const float4* b4 = (const float4*)(bsrc + k0);
        #pragma unroll
        for (int j = 0; j < 8; j++) bv[j] = b4[j];
    };
    auto stageA = [&](int k0, int buf) {
        #pragma unroll
        for (int i = 0; i < 4; i++)
            async_load16(asrc[i] + k0, lA0 + buf * 8192 + aofs[i]);
    };
    auto writeB = [&](int buf) {
        #pragma unroll
        for (int j = 0; j < 4; j++) {
            uint4 p;
            p.x = pack_bf16x2(bv[2 * j].x, bv[2 * j].y);
            p.y = pack_bf16x2(bv[2 * j].z, bv[2 * j].w);
            p.z = pack_bf16x2(bv[2 * j + 1].x, bv[2 * j + 1].y);
            p.w = pack_bf16x2(bv[2 * j + 1].z, bv[2 * j + 1].w);
            *(uint4*)(lB0 + buf * 8192 + bofs[j]) = p;
        }
    };

    const int wr = wv >> 1, wc = wv & 1;
    const int quad = ln >> 4, lq = ln & 15;
    floatx4 acc[4][4] = {};
    auto compute = [&](int buf) {
        #pragma unroll
        for (int kk = 0; kk < 64; kk += 32) {
            short8 af[4], bf[4];
            #pragma unroll
            for (int mi = 0; mi < 4; mi++)
                af[mi] = *(const short8*)(lA0 + buf * 8192 + (wr * 64 + mi * 16 + lq) * 64
                                          + ((((kk >> 3) + quad) ^ (lq & 7)) << 3));
            #pragma unroll
            for (int ni = 0; ni < 4; ni++)
                bf[ni] = *(const short8*)(lB0 + buf * 8192 + (wc * 64 + ni * 16 + lq) * 64
                                          + ((((kk >> 3) + quad) ^ (lq & 7)) << 3));
            #pragma unroll
            for (int mi = 0; mi < 4; mi++)
                #pragma unroll
                for (int ni = 0; ni < 4; ni++)
                    acc[mi][ni] = __builtin_amdgcn_mfma_f32_16x16x32_bf16(af[mi], bf[ni], acc[mi][ni], 0, 0, 0);
        }
    };

    loadB(0);
    stageA(0, 0);
    writeB(0);
    __syncthreads();
    for (int t = 0; t < 31; ++t) {
        const int cur = t & 1, nxt = cur ^ 1;
        const int k0 = (t + 1) * 64;
        loadB(k0);
        stageA(k0, nxt);
        compute(cur);
        writeB(nxt);
        __syncthreads();
    }
    compute(1);            // t = 31

    // epilogue: weighted scatter-add into out (residual already = x)
    #pragma unroll
    for (int mi = 0; mi < 4; mi++) {
        #pragma unroll
        for (int r = 0; r < 4; r++) {
            int slot = mt * 128 + wr * 64 + mi * 16 + quad * 4 + r;
            int tok = tok_slot[e * CAP + slot];
            if (tok < 0) continue;
            float wgt = w_slot[e * CAP + slot];
            float* op = out + (size_t)tok * H + nt * 128 + wc * 64 + lq;
            #pragma unroll
            for (int ni = 0; ni < 4; ni++)
                unsafeAtomicAdd(&op[ni * 16], wgt * acc[mi][ni][r]);
        }
    }
}

extern "C" void kernel_launch(void* const* d_in, const int* in_sizes, int n_in,
                              void* d_out, int out_size, void* d_ws, size_t ws_size,
                              hipStream_t stream) {
    const float* x        = (const float*)d_in[0];
    const float* rms_w    = (const float*)d_in[1];
    const float* router_w = (const float*)d_in[2];
    const float* w1       = (const float*)d_in[3];
    const float* w2       = (const float*)d_in[4];
    float* out = (float*)d_out;

    char* ws = (char*)d_ws;
    u16* xn    = (u16*)ws;                                  // 16 MB  (S*H bf16)
    u16* hbuf  = (u16*)(ws + ((size_t)16 << 20));           // 128 MB (E*CAP*DFF bf16)
    int* cnt      = (int*)(ws + ((size_t)144 << 20));       // 256 B
    int* tok_slot = (int*)(ws + ((size_t)144 << 20) + 4096);            // 128 KB
    float* w_slot = (float*)(ws + ((size_t)144 << 20) + 4096 + (size_t)E * CAP * 4);

    k_init<<<dim3((E * CAP + 255) / 256), 256, 0, stream>>>(cnt, tok_slot);
    k_rms_router<<<dim3(S / 8), 256, 0, stream>>>(x, rms_w, router_w, out, xn, cnt, tok_slot, w_slot);
    k_gemm1<<<dim3(64, E), 256, 0, stream>>>(xn, w1, hbuf, cnt, tok_slot);
    k_gemm2<<<dim3(32, E), 256, 0, stream>>>(hbuf, w2, out, cnt, tok_slot, w_slot);
}